// Round 6
// baseline (106.163 us; speedup 1.0000x reference)
//
#include <hip/hip_runtime.h>
#include <hip/hip_bf16.h>

// x:[16,64,128,128] f32 -> stats -> MLP -> per-sample kern[64,64,3,3] -> conv(pad=1)
// bf16 MFMA implicit GEMM. xT[b][y][130 xi][64 ci] bf16 (x-padded zero cols),
// wT[b][co][tap][ci] bf16.
// R6: conv streams weight frags from L2 (6 in flight, bounded by loop structure)
// instead of trying to hold 72+ regs (R4/R5 showed the allocator remats them).
// x-LDS identical to R5 (conflict-free). 50.7KB LDS + ~90 VGPR -> 3 blocks/CU.

#define B_ 16
#define CI_ 64
#define CO_ 64
#define HW_ 128
#define NPIX 16384
#define KEL 36864
#define XT_RS 8320          // 130 * 64 shorts per padded row

typedef __attribute__((ext_vector_type(4))) float f32x4;
typedef __attribute__((ext_vector_type(8))) short short8;

static __device__ __forceinline__ short bf16_of(float f) {
    __hip_bfloat16 h = __float2bfloat16(f);
    return *reinterpret_cast<short*>(&h);
}

// ---------- Kernel 1: transpose x -> xT bf16 [b][y][130][64]; partial stats ----------
__global__ __launch_bounds__(256) void xpose_stats(const float* __restrict__ x,
                                                   short* __restrict__ xT,
                                                   float* __restrict__ part) {
    int b = blockIdx.x, cig = blockIdx.y, pt = blockIdx.z;
    int t = threadIdx.x;
    int y = pt * 8 + (t >> 5);
    int x0 = (t & 31) * 4;

    const float* xb = x + ((size_t)(b * 64 + cig * 8)) * NPIX;
    short* xTb = xT + (size_t)b * 128 * XT_RS;

    float s[8], ss[8];
    f32x4 v[8];
    #pragma unroll
    for (int c = 0; c < 8; c++) {
        v[c] = *(const f32x4*)(xb + (size_t)c * NPIX + y * 128 + x0);
        s[c]  = v[c][0] + v[c][1] + v[c][2] + v[c][3];
        ss[c] = v[c][0]*v[c][0] + v[c][1]*v[c][1] + v[c][2]*v[c][2] + v[c][3]*v[c][3];
    }
    #pragma unroll
    for (int xi = 0; xi < 4; xi++) {
        short8 o;
        #pragma unroll
        for (int c = 0; c < 8; c++) o[c] = bf16_of(v[c][xi]);
        *(short8*)(xTb + ((size_t)(y * 130 + x0 + xi + 1)) * 64 + cig * 8) = o;
    }
    // zero-pad columns xi=0 and xi=129 (x halo)
    if (t < 16) {
        int y2 = pt * 8 + (t & 7);
        int col = (t & 8) ? 129 : 0;
        short8 z = {0, 0, 0, 0, 0, 0, 0, 0};
        *(short8*)(xTb + ((size_t)(y2 * 130 + col)) * 64 + cig * 8) = z;
    }

    __shared__ float red[4][16];
    int lane = t & 63, w = t >> 6;
    #pragma unroll
    for (int c = 0; c < 8; c++) {
        float a = s[c], q = ss[c];
        for (int off = 32; off; off >>= 1) { a += __shfl_down(a, off); q += __shfl_down(q, off); }
        if (lane == 0) { red[w][c * 2] = a; red[w][c * 2 + 1] = q; }
    }
    __syncthreads();
    if (t < 16)
        part[((size_t)((b * 8 + cig) * 16 + pt)) * 16 + t] =
            red[0][t] + red[1][t] + red[2][t] + red[3][t];
}

// ---------- Kernel 2: stats+h for ALL b (redundant, cheap); wT = bf16(h@w2+b2) ----------
__global__ __launch_bounds__(256) void kern_gen(const float* __restrict__ part,
                                                const float* __restrict__ w1,
                                                const float* __restrict__ b1,
                                                const float* __restrict__ w2,
                                                const float* __restrict__ b2,
                                                short* __restrict__ wT) {
    int chunk = blockIdx.x, bq = blockIdx.y;
    __shared__ float st[16][128];
    __shared__ float h[16][32];
    int t = threadIdx.x;

    for (int id = t; id < 1024; id += 256) {
        int b = id >> 6, ci = id & 63;
        const float* pb = part + ((size_t)((b * 8 + (ci >> 3)) * 16)) * 16 + (ci & 7) * 2;
        float s = 0.f, q = 0.f;
        #pragma unroll
        for (int p = 0; p < 16; p++) { s += pb[p * 16]; q += pb[p * 16 + 1]; }
        float mean = s * (1.f / NPIX);
        float var = fmaxf((q - s * mean) * (1.f / (NPIX - 1)), 0.f);
        st[b][ci] = mean;
        st[b][64 + ci] = sqrtf(var);
    }
    __syncthreads();
    for (int id = t; id < 512; id += 256) {
        int b = id >> 5, j = id & 31;
        float acc = b1[j];
        for (int i = 0; i < 128; i++) acc += st[b][i] * w1[i * 32 + j];
        h[b][j] = fmaxf(acc, 0.f);
    }
    __syncthreads();

    int jbase = chunk * 2304;
    float acc[9][4];
    #pragma unroll
    for (int tp = 0; tp < 9; tp++) {
        float bv = b2[jbase + tp * 256 + t];
        #pragma unroll
        for (int bb = 0; bb < 4; bb++) acc[tp][bb] = bv;
    }
    for (int i = 0; i < 32; i++) {
        const float* w2r = w2 + (size_t)i * KEL + jbase + t;
        float hv[4];
        #pragma unroll
        for (int bb = 0; bb < 4; bb++) hv[bb] = h[bq * 4 + bb][i];
        #pragma unroll
        for (int tp = 0; tp < 9; tp++) {
            float wv = w2r[tp * 256];
            #pragma unroll
            for (int bb = 0; bb < 4; bb++) acc[tp][bb] += hv[bb] * wv;
        }
    }
    #pragma unroll
    for (int tp = 0; tp < 9; tp++) {
        int j = jbase + tp * 256 + t;              // j = (co*64+ci)*9 + tap
        int co = j / 576;
        int rem = j - co * 576;
        int ci = rem / 9;
        int tap = rem - ci * 9;
        #pragma unroll
        for (int bb = 0; bb < 4; bb++)
            wT[(size_t)(bq * 4 + bb) * KEL + co * 576 + tap * 64 + ci] = bf16_of(acc[tp][bb]);
    }
}

// ---------- Kernel 3: conv via MFMA, weights streamed from L2 ----------
// grid (xt=2, yt=32, b=16), 512 thr (8 waves). Wave w: ch=w&1 (32 co), r=w>>1.
// LDS [6][66][64] bf16 = 50.7 KB, XOR slot swizzle -> conflict-free b128 reads.
// Loop: kp(u1) -> dy(u1) -> {6 wf loads; n(4) x dx(3): ds_read + 2 MFMA}.
__global__ __launch_bounds__(512, 4) void conv_mfma(const short* __restrict__ xT,
                                                    const short* __restrict__ wT,
                                                    float* __restrict__ out) {
    __shared__ __align__(16) short xls[6][66][64];

    int xt = blockIdx.x, ytile = blockIdx.y, b = blockIdx.z;
    int x0 = xt * 64, y0 = ytile * 4;
    int t = threadIdx.x;
    int l = t & 63, w = t >> 6;
    int ch = w & 1, r = w >> 1;
    int l15 = l & 15, lg = l >> 4;

    // ---- stage 6 rows x 66 cols (from padded xT; y-OOB -> 0) ----
    const short* xTb = xT + (size_t)b * 128 * XT_RS;
    #pragma unroll
    for (int it = 0; it < 7; it++) {
        int e = it * 512 + t;
        if (e < 3168) {                     // 6*66*8
            int lr = e / 528;
            int rem = e - lr * 528;
            int xcol = rem >> 3, slot = rem & 7;
            int y = y0 - 1 + lr;
            short8 v = {0, 0, 0, 0, 0, 0, 0, 0};
            if ((unsigned)y < 128u)
                v = *(const short8*)(xTb + (size_t)y * XT_RS + (x0 + xcol) * 64 + slot * 8);
            *(short8*)&xls[lr][xcol][(slot ^ (xcol & 7)) << 3] = v;
        }
    }
    __syncthreads();

    const short* wTb = wT + ((size_t)(b * 64 + ch * 32 + l15)) * 576 + lg * 8;

    f32x4 acc[4][2];
    #pragma unroll
    for (int n = 0; n < 4; n++)
        #pragma unroll
        for (int g = 0; g < 2; g++) acc[n][g] = (f32x4){0.f, 0.f, 0.f, 0.f};

    #pragma unroll 1
    for (int kp = 0; kp < 2; kp++) {
        #pragma unroll 1
        for (int dy = 0; dy < 3; dy++) {
            // 6 weight frags in flight (24 VGPR): [g][dx]
            short8 wf[2][3];
            #pragma unroll
            for (int g = 0; g < 2; g++)
                #pragma unroll
                for (int dx = 0; dx < 3; dx++)
                    wf[g][dx] = *(const short8*)(wTb + g * 16 * 576 + (dy * 3 + dx) * 64 + kp * 32);

            const short* xrow = &xls[r + dy][0][0];
            #pragma unroll
            for (int n = 0; n < 4; n++) {
                #pragma unroll
                for (int dx = 0; dx < 3; dx++) {
                    int xi = n * 16 + l15 + dx;                 // 0..65
                    short8 bf = *(const short8*)&xrow[xi * 64 + (((kp * 4 + lg) ^ (xi & 7)) << 3)];
                    acc[n][0] = __builtin_amdgcn_mfma_f32_16x16x32_bf16(wf[0][dx], bf, acc[n][0], 0, 0, 0);
                    acc[n][1] = __builtin_amdgcn_mfma_f32_16x16x32_bf16(wf[1][dx], bf, acc[n][1], 0, 0, 0);
                }
            }
        }
    }

    // ---- store 2 co-groups x 4 regs x 4 n-tiles ----
    #pragma unroll
    for (int g = 0; g < 2; g++) {
        float* ob = out + ((size_t)(b * 64 + ch * 32 + g * 16 + lg * 4)) * NPIX
                        + (y0 + r) * 128 + x0 + l15;
        #pragma unroll
        for (int reg = 0; reg < 4; reg++)
            #pragma unroll
            for (int n = 0; n < 4; n++)
                ob[(size_t)reg * NPIX + n * 16] = acc[n][g][reg];
    }
}

extern "C" void kernel_launch(void* const* d_in, const int* in_sizes, int n_in,
                              void* d_out, int out_size, void* d_ws, size_t ws_size,
                              hipStream_t stream) {
    const float* x  = (const float*)d_in[0];
    const float* w1 = (const float*)d_in[1];
    const float* b1 = (const float*)d_in[2];
    const float* w2 = (const float*)d_in[3];
    const float* b2 = (const float*)d_in[4];
    float* out = (float*)d_out;

    float* part = (float*)d_ws;                                   // 128 KB
    short* wT = (short*)((char*)d_ws + 131072);                   // 1.18 MB
    short* xT = (short*)((char*)d_ws + 131072 + 1179648);         // 34.1 MB

    xpose_stats<<<dim3(B_, 8, 16), 256, 0, stream>>>(x, xT, part);
    kern_gen<<<dim3(16, 4), 256, 0, stream>>>(part, w1, b1, w2, b2, wT);
    conv_mfma<<<dim3(2, 32, B_), 512, 0, stream>>>(xT, wT, out);
}

// Round 7
// 91.024 us; speedup vs baseline: 1.1663x; 1.1663x over previous
//
#include <hip/hip_runtime.h>
#include <hip/hip_bf16.h>

// x:[16,64,128,128] f32 -> stats -> MLP -> per-sample kern[64,64,3,3] -> conv(pad=1)
// bf16 MFMA implicit GEMM. xT[b][y][130 xi][64 ci] bf16 (x-padded zero cols),
// wT[b][co][tap][ci] bf16.
// R7: conv = persistent block (4 y-subtiles), double-buffered global_load_lds
// staging (swizzled SOURCE, linear LDS dest), weights preloaded into VGPRs and
// PINNED with empty asm (+v) so the allocator cannot rematerialize them
// (R4/R5/R6 all showed remat when unpinned). 1 block/CU, 256-VGPR budget.
// kern_gen back to 256 blocks (chunk x b).

#define B_ 16
#define NPIX 16384
#define KEL 36864
#define XT_RS 8320          // 130 * 64 shorts per padded row

typedef __attribute__((ext_vector_type(4))) float f32x4;
typedef __attribute__((ext_vector_type(8))) short short8;

static __device__ __forceinline__ short bf16_of(float f) {
    __hip_bfloat16 h = __float2bfloat16(f);
    return *reinterpret_cast<short*>(&h);
}

// ---------- Kernel 1: transpose x -> xT bf16 [b][y][130][64]; partial stats ----------
__global__ __launch_bounds__(256) void xpose_stats(const float* __restrict__ x,
                                                   short* __restrict__ xT,
                                                   float* __restrict__ part) {
    int b = blockIdx.x, cig = blockIdx.y, pt = blockIdx.z;
    int t = threadIdx.x;
    int y = pt * 8 + (t >> 5);
    int x0 = (t & 31) * 4;

    const float* xb = x + ((size_t)(b * 64 + cig * 8)) * NPIX;
    short* xTb = xT + (size_t)b * 128 * XT_RS;

    float s[8], ss[8];
    f32x4 v[8];
    #pragma unroll
    for (int c = 0; c < 8; c++) {
        v[c] = *(const f32x4*)(xb + (size_t)c * NPIX + y * 128 + x0);
        s[c]  = v[c][0] + v[c][1] + v[c][2] + v[c][3];
        ss[c] = v[c][0]*v[c][0] + v[c][1]*v[c][1] + v[c][2]*v[c][2] + v[c][3]*v[c][3];
    }
    #pragma unroll
    for (int xi = 0; xi < 4; xi++) {
        short8 o;
        #pragma unroll
        for (int c = 0; c < 8; c++) o[c] = bf16_of(v[c][xi]);
        *(short8*)(xTb + ((size_t)(y * 130 + x0 + xi + 1)) * 64 + cig * 8) = o;
    }
    // zero-pad columns xi=0 and xi=129 (x halo)
    if (t < 16) {
        int y2 = pt * 8 + (t & 7);
        int col = (t & 8) ? 129 : 0;
        short8 z = {0, 0, 0, 0, 0, 0, 0, 0};
        *(short8*)(xTb + ((size_t)(y2 * 130 + col)) * 64 + cig * 8) = z;
    }

    __shared__ float red[4][16];
    int lane = t & 63, w = t >> 6;
    #pragma unroll
    for (int c = 0; c < 8; c++) {
        float a = s[c], q = ss[c];
        for (int off = 32; off; off >>= 1) { a += __shfl_down(a, off); q += __shfl_down(q, off); }
        if (lane == 0) { red[w][c * 2] = a; red[w][c * 2 + 1] = q; }
    }
    __syncthreads();
    if (t < 16)
        part[((size_t)((b * 8 + cig) * 16 + pt)) * 16 + t] =
            red[0][t] + red[1][t] + red[2][t] + red[3][t];
}

// ---------- Kernel 2: per-b stats + MLP; wT[b][co][tap][ci] = bf16(h@w2+b2) ----------
// grid (chunk=16, b=16) = 256 blocks.
__global__ __launch_bounds__(256) void kern_gen(const float* __restrict__ part,
                                                const float* __restrict__ w1,
                                                const float* __restrict__ b1,
                                                const float* __restrict__ w2,
                                                const float* __restrict__ b2,
                                                short* __restrict__ wT) {
    int chunk = blockIdx.x, b = blockIdx.y;
    __shared__ float st[128];
    __shared__ float h[32];
    int t = threadIdx.x;
    if (t < 64) {                       // per-ci reduction of 16 partials
        int cig = t >> 3, cl = t & 7;
        const float* pb = part + ((size_t)((b * 8 + cig) * 16)) * 16 + cl * 2;
        float s = 0.f, q = 0.f;
        #pragma unroll
        for (int p = 0; p < 16; p++) { s += pb[p * 16]; q += pb[p * 16 + 1]; }
        float mean = s * (1.f / NPIX);
        float var = fmaxf((q - s * mean) * (1.f / (NPIX - 1)), 0.f);
        st[t] = mean;
        st[64 + t] = sqrtf(var);
    }
    __syncthreads();
    if (t < 32) {
        float acc = b1[t];
        for (int i = 0; i < 128; i++) acc += st[i] * w1[i * 32 + t];
        h[t] = fmaxf(acc, 0.f);
    }
    __syncthreads();

    int jbase = chunk * 2304;
    float acc[9];
    #pragma unroll
    for (int tp = 0; tp < 9; tp++) acc[tp] = b2[jbase + tp * 256 + t];
    for (int i = 0; i < 32; i++) {
        float hi = h[i];
        const float* w2r = w2 + (size_t)i * KEL + jbase + t;
        #pragma unroll
        for (int tp = 0; tp < 9; tp++) acc[tp] += hi * w2r[tp * 256];
    }
    short* wb = wT + (size_t)b * KEL;
    #pragma unroll
    for (int tp = 0; tp < 9; tp++) {
        int j = jbase + tp * 256 + t;              // j = (co*64+ci)*9 + tap
        int co = j / 576;
        int rem = j - co * 576;
        int ci = rem / 9;
        int tap = rem - ci * 9;
        wb[co * 576 + tap * 64 + ci] = bf16_of(acc[tp]);
    }
}

// ---------- Kernel 3: conv via MFMA, persistent 4-subtile blocks, dbuf LDS ----------
// grid (b=16, xt=2, ytg=8) = 256 blocks = 1/CU. 512 thr (8 waves).
// Wave w: ch=w&1 (32 co), r=w>>1 (row). Per sub-tile: 4 rows x 64 px x 64 co.
// LDS: 2 bufs x [6 rows][66 xi][8 slots] x 16B = 101376 B.
// Slot swizzle: LDS (xi, p) holds source ci-slot p^(xi&7); read (kp*4+lg)^(xi&7).
__global__ __launch_bounds__(512, 2) void conv_mfma(const short* __restrict__ xT,
                                                    const short* __restrict__ wT,
                                                    float* __restrict__ out) {
    __shared__ __align__(16) short xls[2][25344];   // 6*528 slots * 8 shorts

    int b = blockIdx.x, xt = blockIdx.y, ytg = blockIdx.z;
    int x0 = xt * 64;
    int t = threadIdx.x;
    int l = t & 63, w = t >> 6;
    int ch = w & 1, r = w >> 1;
    int l15 = l & 15, lg = l >> 4;

    const short* xTb = xT + (size_t)b * 128 * XT_RS;

    // ---- issue weight preload (36 frags, from L2) ----
    const short* wTb = wT + ((size_t)(b * 64 + ch * 32 + l15)) * 576 + lg * 8;
    short8 wf[2][9][2];
    #pragma unroll
    for (int g = 0; g < 2; g++)
        #pragma unroll
        for (int tap = 0; tap < 9; tap++)
            #pragma unroll
            for (int kp = 0; kp < 2; kp++)
                wf[g][tap][kp] = *(const short8*)(wTb + g * 16 * 576 + tap * 64 + kp * 32);

#define STAGE(i_)                                                               \
    {                                                                           \
        int y0s = (ytg * 4 + (i_)) * 4;                                         \
        short* bufp = &xls[(i_) & 1][0];                                        \
        if (y0s == 0 || y0s == 124) {      /* zero the OOB halo row */          \
            int oobr = (y0s == 0) ? 0 : 5;                                      \
            short8 z8 = {0, 0, 0, 0, 0, 0, 0, 0};                               \
            for (int e = t; e < 528; e += 512)                                  \
                *(short8*)(bufp + (oobr * 528 + e) * 8) = z8;                   \
        }                                                                       \
        _Pragma("unroll")                                                       \
        for (int it = 0; it < 7; it++) {                                        \
            int e = it * 512 + t;                                               \
            if (e < 3168) {                                                     \
                int lr = e / 528;                                               \
                int rem = e - lr * 528;                                         \
                int xcol = rem >> 3, sslot = rem & 7;                           \
                int y = y0s - 1 + lr;                                           \
                if ((unsigned)y < 128u) {                                       \
                    const short* src = xTb + (size_t)y * XT_RS                  \
                        + (x0 + xcol) * 64 + ((sslot ^ (xcol & 7)) << 3);       \
                    __builtin_amdgcn_global_load_lds(                           \
                        (const __attribute__((address_space(1))) void*)src,     \
                        (__attribute__((address_space(3))) void*)                \
                            (bufp + ((it * 512 + (t & ~63))) * 8),              \
                        16, 0, 0);                                              \
                }                                                               \
            }                                                                   \
        }                                                                       \
    }

    STAGE(0);

    // ---- pin weights: opaque asm result cannot be rematerialized ----
    #pragma unroll
    for (int g = 0; g < 2; g++)
        #pragma unroll
        for (int tap = 0; tap < 9; tap++)
            #pragma unroll
            for (int kp = 0; kp < 2; kp++)
                asm volatile("" : "+v"(wf[g][tap][kp]));

    asm volatile("s_waitcnt vmcnt(0)" ::: "memory");
    __syncthreads();

    #pragma unroll 1
    for (int i = 0; i < 4; i++) {
        if (i < 3) STAGE(i + 1);          // async fill of other buffer

        const short* bufc = &xls[i & 1][0];
        int y0 = (ytg * 4 + i) * 4;

        f32x4 acc[4][2];
        #pragma unroll
        for (int n = 0; n < 4; n++)
            #pragma unroll
            for (int g = 0; g < 2; g++) acc[n][g] = (f32x4){0.f, 0.f, 0.f, 0.f};

        #pragma unroll
        for (int kp = 0; kp < 2; kp++) {
            #pragma unroll
            for (int n = 0; n < 4; n++) {
                #pragma unroll
                for (int tap = 0; tap < 9; tap++) {
                    const int dy = tap / 3, dx = tap % 3;
                    int xi = n * 16 + l15 + dx;                 // 0..65
                    short8 bf = *(const short8*)&bufc[((r + dy) * 528 + xi * 8
                                    + (((kp * 4 + lg) ^ (xi & 7)))) * 8];
                    acc[n][0] = __builtin_amdgcn_mfma_f32_16x16x32_bf16(wf[0][tap][kp], bf, acc[n][0], 0, 0, 0);
                    acc[n][1] = __builtin_amdgcn_mfma_f32_16x16x32_bf16(wf[1][tap][kp], bf, acc[n][1], 0, 0, 0);
                }
            }
        }

        // ---- store ----
        #pragma unroll
        for (int g = 0; g < 2; g++) {
            float* ob = out + ((size_t)(b * 64 + ch * 32 + g * 16 + lg * 4)) * NPIX
                            + (y0 + r) * 128 + x0 + l15;
            #pragma unroll
            for (int reg = 0; reg < 4; reg++)
                #pragma unroll
                for (int n = 0; n < 4; n++)
                    ob[(size_t)reg * NPIX + n * 16] = acc[n][g][reg];
        }

        if (i < 3) {
            asm volatile("s_waitcnt vmcnt(0)" ::: "memory");   // stage(i+1) landed
            __syncthreads();                                    // all done with buf[i&1]
        }
    }
#undef STAGE
}

extern "C" void kernel_launch(void* const* d_in, const int* in_sizes, int n_in,
                              void* d_out, int out_size, void* d_ws, size_t ws_size,
                              hipStream_t stream) {
    const float* x  = (const float*)d_in[0];
    const float* w1 = (const float*)d_in[1];
    const float* b1 = (const float*)d_in[2];
    const float* w2 = (const float*)d_in[3];
    const float* b2 = (const float*)d_in[4];
    float* out = (float*)d_out;

    float* part = (float*)d_ws;                                   // 128 KB
    short* wT = (short*)((char*)d_ws + 131072);                   // 1.18 MB
    short* xT = (short*)((char*)d_ws + 131072 + 1179648);         // 34.1 MB

    xpose_stats<<<dim3(B_, 8, 16), 256, 0, stream>>>(x, xT, part);
    kern_gen<<<dim3(16, B_), 256, 0, stream>>>(part, w1, b1, w2, b2, wT);
    conv_mfma<<<dim3(B_, 2, 8), 512, 0, stream>>>(xT, wT, out);
}

// Round 8
// 69.553 us; speedup vs baseline: 1.5264x; 1.3087x over previous
//
#include <hip/hip_runtime.h>
#include <hip/hip_bf16.h>

// x:[16,64,128,128] f32 -> stats -> MLP -> per-sample kern[64,64,3,3] -> conv(pad=1)
// bf16 MFMA implicit GEMM. xT[b][y][130 xi][64 ci] bf16 (x-padded zero cols),
// wT[b][co][tap][ci] bf16.
// R8: conv keeps BOTH weights and x-tile in LDS (127 KB). No register-resident
// weights -> nothing for the allocator to remat/spill (R4-R7 all lost to it).
// A-frags re-read from LDS per (kp,tap): 0.75 ds_read_b128/MFMA, 2-way banks.

#define B_ 16
#define NPIX 16384
#define KEL 36864
#define XT_RS 8320          // 130 * 64 shorts per padded row

typedef __attribute__((ext_vector_type(4))) float f32x4;
typedef __attribute__((ext_vector_type(8))) short short8;

static __device__ __forceinline__ short bf16_of(float f) {
    __hip_bfloat16 h = __float2bfloat16(f);
    return *reinterpret_cast<short*>(&h);
}

// ---------- Kernel 1: transpose x -> xT bf16 [b][y][130][64]; partial stats ----------
__global__ __launch_bounds__(256) void xpose_stats(const float* __restrict__ x,
                                                   short* __restrict__ xT,
                                                   float* __restrict__ part) {
    int b = blockIdx.x, cig = blockIdx.y, pt = blockIdx.z;
    int t = threadIdx.x;
    int y = pt * 8 + (t >> 5);
    int x0 = (t & 31) * 4;

    const float* xb = x + ((size_t)(b * 64 + cig * 8)) * NPIX;
    short* xTb = xT + (size_t)b * 128 * XT_RS;

    float s[8], ss[8];
    f32x4 v[8];
    #pragma unroll
    for (int c = 0; c < 8; c++) {
        v[c] = *(const f32x4*)(xb + (size_t)c * NPIX + y * 128 + x0);
        s[c]  = v[c][0] + v[c][1] + v[c][2] + v[c][3];
        ss[c] = v[c][0]*v[c][0] + v[c][1]*v[c][1] + v[c][2]*v[c][2] + v[c][3]*v[c][3];
    }
    #pragma unroll
    for (int xi = 0; xi < 4; xi++) {
        short8 o;
        #pragma unroll
        for (int c = 0; c < 8; c++) o[c] = bf16_of(v[c][xi]);
        *(short8*)(xTb + ((size_t)(y * 130 + x0 + xi + 1)) * 64 + cig * 8) = o;
    }
    // zero-pad columns xi=0 and xi=129 (x halo)
    if (t < 16) {
        int y2 = pt * 8 + (t & 7);
        int col = (t & 8) ? 129 : 0;
        short8 z = {0, 0, 0, 0, 0, 0, 0, 0};
        *(short8*)(xTb + ((size_t)(y2 * 130 + col)) * 64 + cig * 8) = z;
    }

    __shared__ float red[4][16];
    int lane = t & 63, w = t >> 6;
    #pragma unroll
    for (int c = 0; c < 8; c++) {
        float a = s[c], q = ss[c];
        for (int off = 32; off; off >>= 1) { a += __shfl_down(a, off); q += __shfl_down(q, off); }
        if (lane == 0) { red[w][c * 2] = a; red[w][c * 2 + 1] = q; }
    }
    __syncthreads();
    if (t < 16)
        part[((size_t)((b * 8 + cig) * 16 + pt)) * 16 + t] =
            red[0][t] + red[1][t] + red[2][t] + red[3][t];
}

// ---------- Kernel 2: per-b stats + MLP; wT[b][co][tap][ci] = bf16(h@w2+b2) ----------
__global__ __launch_bounds__(256) void kern_gen(const float* __restrict__ part,
                                                const float* __restrict__ w1,
                                                const float* __restrict__ b1,
                                                const float* __restrict__ w2,
                                                const float* __restrict__ b2,
                                                short* __restrict__ wT) {
    int chunk = blockIdx.x, b = blockIdx.y;
    __shared__ float st[128];
    __shared__ float h[32];
    int t = threadIdx.x;
    if (t < 64) {
        int cig = t >> 3, cl = t & 7;
        const float* pb = part + ((size_t)((b * 8 + cig) * 16)) * 16 + cl * 2;
        float s = 0.f, q = 0.f;
        #pragma unroll
        for (int p = 0; p < 16; p++) { s += pb[p * 16]; q += pb[p * 16 + 1]; }
        float mean = s * (1.f / NPIX);
        float var = fmaxf((q - s * mean) * (1.f / (NPIX - 1)), 0.f);
        st[t] = mean;
        st[64 + t] = sqrtf(var);
    }
    __syncthreads();
    if (t < 32) {
        float acc = b1[t];
        for (int i = 0; i < 128; i++) acc += st[i] * w1[i * 32 + t];
        h[t] = fmaxf(acc, 0.f);
    }
    __syncthreads();

    int jbase = chunk * 2304;
    float acc[9];
    #pragma unroll
    for (int tp = 0; tp < 9; tp++) acc[tp] = b2[jbase + tp * 256 + t];
    for (int i = 0; i < 32; i++) {
        float hi = h[i];
        const float* w2r = w2 + (size_t)i * KEL + jbase + t;
        #pragma unroll
        for (int tp = 0; tp < 9; tp++) acc[tp] += hi * w2r[tp * 256];
    }
    short* wb = wT + (size_t)b * KEL;
    #pragma unroll
    for (int tp = 0; tp < 9; tp++) {
        int j = jbase + tp * 256 + t;              // j = (co*64+ci)*9 + tap
        int co = j / 576;
        int rem = j - co * 576;
        int ci = rem / 9;
        int tap = rem - ci * 9;
        wb[co * 576 + tap * 64 + ci] = bf16_of(acc[tp]);
    }
}

// ---------- Kernel 3: conv via MFMA, weights + x both in LDS ----------
// grid (b=16, xt=2, yt=32) = 1024 blocks (XCD = b%8, matches xpose's writes).
// 512 thr (8 waves): wave w -> ch=w&1 (32-co half), r=w>>1 (row).
// LDS: xls[6][66][64] (50688 B, XOR slot swizzle) + wls[64][594] (76032 B).
// wls row = 9 taps * 66 shorts (pad 66 -> A-frag banks 9*l15+4*lg mod 32, 2-way).
__global__ __launch_bounds__(512, 2) void conv_mfma(const short* __restrict__ xT,
                                                    const short* __restrict__ wT,
                                                    float* __restrict__ out) {
    __shared__ __align__(16) short xls[6][66][64];
    __shared__ __align__(16) short wls[64][594];

    int b = blockIdx.x, xt = blockIdx.y, ytile = blockIdx.z;
    int x0 = xt * 64, y0 = ytile * 4;
    int t = threadIdx.x;
    int l = t & 63, w = t >> 6;
    int ch = w & 1, r = w >> 1;
    int l15 = l & 15, lg = l >> 4;

    // ---- stage x-tile: 6 rows x 66 cols (from padded xT; y-OOB -> 0) ----
    const short* xTb = xT + (size_t)b * 128 * XT_RS;
    #pragma unroll
    for (int it = 0; it < 7; it++) {
        int e = it * 512 + t;
        if (e < 3168) {                     // 6*66*8
            int lr = e / 528;
            int rem = e - lr * 528;
            int xcol = rem >> 3, slot = rem & 7;
            int y = y0 - 1 + lr;
            short8 v = {0, 0, 0, 0, 0, 0, 0, 0};
            if ((unsigned)y < 128u)
                v = *(const short8*)(xTb + (size_t)y * XT_RS + (x0 + xcol) * 64 + slot * 8);
            *(short8*)&xls[lr][xcol][(slot ^ (xcol & 7)) << 3] = v;
        }
    }
    // ---- stage weights: 64 co x 9 tap x 64 ci -> wls[co][tap*66 + ci] ----
    const short* wTb = wT + (size_t)b * KEL;
    #pragma unroll
    for (int it = 0; it < 9; it++) {
        int e = it * 512 + t;               // 0..4607
        int co = e / 72;
        int rem = e - co * 72;
        int tap = rem >> 3, s = rem & 7;
        short8 v = *(const short8*)(wTb + co * 576 + tap * 64 + s * 8);
        *(short8*)&wls[co][tap * 66 + s * 8] = v;
    }
    __syncthreads();

    f32x4 acc[4][2];
    #pragma unroll
    for (int n = 0; n < 4; n++)
        #pragma unroll
        for (int g = 0; g < 2; g++) acc[n][g] = (f32x4){0.f, 0.f, 0.f, 0.f};

    #pragma unroll
    for (int kp = 0; kp < 2; kp++) {
        #pragma unroll
        for (int tap = 0; tap < 9; tap++) {
            const int dy = tap / 3, dx = tap % 3;
            short8 a0 = *(const short8*)&wls[ch * 32 + l15][tap * 66 + kp * 32 + lg * 8];
            short8 a1 = *(const short8*)&wls[ch * 32 + 16 + l15][tap * 66 + kp * 32 + lg * 8];
            #pragma unroll
            for (int n = 0; n < 4; n++) {
                int xi = n * 16 + l15 + dx;                 // 0..65
                short8 bf = *(const short8*)&xls[r + dy][xi][((kp * 4 + lg) ^ (xi & 7)) << 3];
                acc[n][0] = __builtin_amdgcn_mfma_f32_16x16x32_bf16(a0, bf, acc[n][0], 0, 0, 0);
                acc[n][1] = __builtin_amdgcn_mfma_f32_16x16x32_bf16(a1, bf, acc[n][1], 0, 0, 0);
            }
        }
    }

    // ---- store 2 co-groups x 4 regs x 4 n-tiles ----
    #pragma unroll
    for (int g = 0; g < 2; g++) {
        float* ob = out + ((size_t)(b * 64 + ch * 32 + g * 16 + lg * 4)) * NPIX
                        + (y0 + r) * 128 + x0 + l15;
        #pragma unroll
        for (int reg = 0; reg < 4; reg++)
            #pragma unroll
            for (int n = 0; n < 4; n++)
                ob[(size_t)reg * NPIX + n * 16] = acc[n][g][reg];
    }
}

extern "C" void kernel_launch(void* const* d_in, const int* in_sizes, int n_in,
                              void* d_out, int out_size, void* d_ws, size_t ws_size,
                              hipStream_t stream) {
    const float* x  = (const float*)d_in[0];
    const float* w1 = (const float*)d_in[1];
    const float* b1 = (const float*)d_in[2];
    const float* w2 = (const float*)d_in[3];
    const float* b2 = (const float*)d_in[4];
    float* out = (float*)d_out;

    float* part = (float*)d_ws;                                   // 128 KB
    short* wT = (short*)((char*)d_ws + 131072);                   // 1.18 MB
    short* xT = (short*)((char*)d_ws + 131072 + 1179648);         // 34.1 MB

    xpose_stats<<<dim3(B_, 8, 16), 256, 0, stream>>>(x, xT, part);
    kern_gen<<<dim3(16, B_), 256, 0, stream>>>(part, w1, b1, w2, b2, wT);
    conv_mfma<<<dim3(B_, 2, 32), 512, 0, stream>>>(xT, wT, out);
}

// Round 9
// 64.781 us; speedup vs baseline: 1.6388x; 1.0737x over previous
//
#include <hip/hip_runtime.h>
#include <hip/hip_bf16.h>

// x:[16,64,128,128] f32 -> stats -> MLP -> per-sample kern[64,64,3,3] -> conv(pad=1)
// bf16 MFMA implicit GEMM. xT[b][y][130 xi][64 ci] bf16 (x-padded zero cols).
// wT layout (R9): [b][tap(9)][co(64)][64 ci, 16B-slot s stored at s^(co&7)] --
// exactly conv's wls LDS image, so wls staging is a pure linear DMA.
// R9: kern_gen = 144 j-blocks, w2 read once, all 16 b per block (kills the
// latency-bound 75MB stream). conv = persistent (b,xt) block, 4 y-tiles,
// 10-row ring xls + once-staged wls (158KB LDS), stage(j+1) issued before
// compute(j) so global_load_lds hides under MFMA.

#define B_ 16
#define NPIX 16384
#define KEL 36864
#define XT_RS 8320          // 130 * 64 shorts per padded row

typedef __attribute__((ext_vector_type(4))) float f32x4;
typedef __attribute__((ext_vector_type(8))) short short8;

static __device__ __forceinline__ short bf16_of(float f) {
    __hip_bfloat16 h = __float2bfloat16(f);
    return *reinterpret_cast<short*>(&h);
}

// ---------- Kernel 1: transpose x -> xT bf16 [b][y][130][64]; partial stats ----------
__global__ __launch_bounds__(256) void xpose_stats(const float* __restrict__ x,
                                                   short* __restrict__ xT,
                                                   float* __restrict__ part) {
    int b = blockIdx.x, cig = blockIdx.y, pt = blockIdx.z;
    int t = threadIdx.x;
    int y = pt * 8 + (t >> 5);
    int x0 = (t & 31) * 4;

    const float* xb = x + ((size_t)(b * 64 + cig * 8)) * NPIX;
    short* xTb = xT + (size_t)b * 128 * XT_RS;

    float s[8], ss[8];
    f32x4 v[8];
    #pragma unroll
    for (int c = 0; c < 8; c++) {
        v[c] = *(const f32x4*)(xb + (size_t)c * NPIX + y * 128 + x0);
        s[c]  = v[c][0] + v[c][1] + v[c][2] + v[c][3];
        ss[c] = v[c][0]*v[c][0] + v[c][1]*v[c][1] + v[c][2]*v[c][2] + v[c][3]*v[c][3];
    }
    #pragma unroll
    for (int xi = 0; xi < 4; xi++) {
        short8 o;
        #pragma unroll
        for (int c = 0; c < 8; c++) o[c] = bf16_of(v[c][xi]);
        *(short8*)(xTb + ((size_t)(y * 130 + x0 + xi + 1)) * 64 + cig * 8) = o;
    }
    // zero-pad columns xi=0 and xi=129 (x halo)
    if (t < 16) {
        int y2 = pt * 8 + (t & 7);
        int col = (t & 8) ? 129 : 0;
        short8 z = {0, 0, 0, 0, 0, 0, 0, 0};
        *(short8*)(xTb + ((size_t)(y2 * 130 + col)) * 64 + cig * 8) = z;
    }

    __shared__ float red[4][16];
    int lane = t & 63, w = t >> 6;
    #pragma unroll
    for (int c = 0; c < 8; c++) {
        float a = s[c], q = ss[c];
        for (int off = 32; off; off >>= 1) { a += __shfl_down(a, off); q += __shfl_down(q, off); }
        if (lane == 0) { red[w][c * 2] = a; red[w][c * 2 + 1] = q; }
    }
    __syncthreads();
    if (t < 16)
        part[((size_t)((b * 8 + cig) * 16 + pt)) * 16 + t] =
            red[0][t] + red[1][t] + red[2][t] + red[3][t];
}

// ---------- Kernel 2: w2 read ONCE; all 16 b per block ----------
// grid (144): thread t -> j = blk*256+t. Stats+MLP redundant per block (cheap).
// hT[32][16] transposed in LDS for float4 reads. Emits pre-swizzled wT.
__global__ __launch_bounds__(256) void kern_gen(const float* __restrict__ part,
                                                const float* __restrict__ w1,
                                                const float* __restrict__ b1,
                                                const float* __restrict__ w2,
                                                const float* __restrict__ b2,
                                                short* __restrict__ wT) {
    __shared__ float st[16][128];
    __shared__ float hT[32][16];
    int t = threadIdx.x;

    for (int id = t; id < 1024; id += 256) {       // stats for all (b, ci)
        int b = id >> 6, ci = id & 63;
        const float* pb = part + ((size_t)((b * 8 + (ci >> 3)) * 16)) * 16 + (ci & 7) * 2;
        float s = 0.f, q = 0.f;
        #pragma unroll
        for (int p = 0; p < 16; p++) { s += pb[p * 16]; q += pb[p * 16 + 1]; }
        float mean = s * (1.f / NPIX);
        float var = fmaxf((q - s * mean) * (1.f / (NPIX - 1)), 0.f);
        st[b][ci] = mean;
        st[b][64 + ci] = sqrtf(var);
    }
    __syncthreads();
    for (int id = t; id < 512; id += 256) {        // h for all (b, 32), transposed
        int b = id >> 5, jj = id & 31;
        float acc = b1[jj];
        for (int i = 0; i < 128; i++) acc += st[b][i] * w1[i * 32 + jj];
        hT[jj][b] = fmaxf(acc, 0.f);
    }
    __syncthreads();

    int j = blockIdx.x * 256 + t;
    float wv[32];
    #pragma unroll
    for (int i = 0; i < 32; i++) wv[i] = w2[(size_t)i * KEL + j];   // 32 indep loads
    float bv = b2[j];

    float acc[16];
    #pragma unroll
    for (int b = 0; b < 16; b++) acc[b] = bv;
    #pragma unroll
    for (int i = 0; i < 32; i++) {
        float wvi = wv[i];
        const f32x4* hr = (const f32x4*)&hT[i][0];
        #pragma unroll
        for (int q4 = 0; q4 < 4; q4++) {
            f32x4 hq = hr[q4];
            acc[q4 * 4 + 0] += hq[0] * wvi;
            acc[q4 * 4 + 1] += hq[1] * wvi;
            acc[q4 * 4 + 2] += hq[2] * wvi;
            acc[q4 * 4 + 3] += hq[3] * wvi;
        }
    }

    // j = (co*64+ci)*9 + tap; store pre-swizzled: [tap][co][ (ci>>3)^(co&7) slot ]
    int co = j / 576;
    int rem = j - co * 576;
    int ci = rem / 9;
    int tap = rem - ci * 9;
    size_t dst = (size_t)tap * 4096 + co * 64 + ((((ci >> 3) ^ (co & 7)) << 3) | (ci & 7));
    #pragma unroll
    for (int b = 0; b < 16; b++)
        wT[(size_t)b * KEL + dst] = bf16_of(acc[b]);
}

// ---------- Kernel 3: conv via MFMA, persistent ring-buffered blocks ----------
// grid (b=16, xt=2, ytg=8) = 256 blocks (1/CU), 512 thr (8 waves).
// Wave w: ch=w&1 (32-co half), r=w>>1 (row). Per tile: 4 rows x 64 px x 64 co.
// LDS: xls ring 10 rows x 66 xi x 64 ci (84480 B) + wls 9x64x64 (73728 B) = 158208 B.
// Both DMA-staged with global_load_lds; wls once, xls 4 rows/tile issued BEFORE
// compute of the previous tile (disjoint ring slots -> no barrier needed at issue).
__global__ __launch_bounds__(512, 2) void conv_mfma(const short* __restrict__ xT,
                                                    const short* __restrict__ wT,
                                                    float* __restrict__ out) {
    __shared__ __align__(16) short xls[10 * 528 * 8];   // slot*528 + xi*8 + p (16B units)
    __shared__ __align__(16) short wls[9 * 512 * 8];    // tap*512 + co*8 + p

    int b = blockIdx.x, xt = blockIdx.y, ytg = blockIdx.z;
    int x0 = xt * 64, Y0 = ytg * 16;
    int t = threadIdx.x;
    int l = t & 63, w = t >> 6;
    int ch = w & 1, r = w >> 1;
    int l15 = l & 15, lg = l >> 4;

    const short* xTb = xT + (size_t)b * 128 * XT_RS;
    const short* wTb = wT + (size_t)b * KEL;

#define ZROW(sl_)                                                              \
    {   short8 z8 = {0, 0, 0, 0, 0, 0, 0, 0};                                  \
        for (int e = t; e < 528; e += 512)                                     \
            *(short8*)(xls + ((sl_) * 528 + e) * 8) = z8; }

#define DMAROW(sl_, y_)                                                        \
    {   _Pragma("unroll")                                                      \
        for (int it = 0; it < 2; it++) {                                       \
            int e = it * 512 + t;                                              \
            if (e < 528) {                                                     \
                int xi = e >> 3, s = e & 7;                                    \
                const short* src = xTb + (size_t)(y_) * XT_RS                  \
                    + (x0 + xi) * 64 + ((s ^ (xi & 7)) << 3);                  \
                __builtin_amdgcn_global_load_lds(                              \
                    (const __attribute__((address_space(1))) void*)src,        \
                    (__attribute__((address_space(3))) void*)                   \
                        (xls + ((sl_) * 528 + it * 512 + (t & ~63)) * 8),      \
                    16, 0, 0);                                                 \
            }                                                                  \
        } }

    // ---- stage wls (pure linear DMA, wT is pre-swizzled) ----
    #pragma unroll
    for (int it = 0; it < 9; it++) {
        int e = it * 512 + t;
        __builtin_amdgcn_global_load_lds(
            (const __attribute__((address_space(1))) void*)(wTb + (size_t)e * 8),
            (__attribute__((address_space(3))) void*)(wls + (it * 512 + (t & ~63)) * 8),
            16, 0, 0);
    }
    // ---- prologue: rows Y0-1 .. Y0+4 into slots 0..5 ----
    #pragma unroll
    for (int k = 0; k < 6; k++) {
        int y = Y0 - 1 + k;
        if (y < 0) { ZROW(k); } else { DMAROW(k, y); }
    }
    asm volatile("s_waitcnt vmcnt(0)" ::: "memory");
    __syncthreads();

    int rbase = 0;
    #pragma unroll 1
    for (int j = 0; j < 4; j++) {
        // ---- issue stage of tile j+1's 4 new rows (slots rbase+6..+9, disjoint) ----
        if (j < 3) {
            #pragma unroll
            for (int m = 0; m < 4; m++) {
                int sl = rbase + 6 + m; if (sl >= 10) sl -= 10;
                int y = Y0 + 4 * j + 5 + m;
                if (y > 127) { ZROW(sl); } else { DMAROW(sl, y); }
            }
        }

        // ---- compute tile j (reads ring slots rbase..rbase+5 and wls) ----
        int y0 = Y0 + 4 * j;
        f32x4 acc[4][2];
        #pragma unroll
        for (int n = 0; n < 4; n++)
            #pragma unroll
            for (int g = 0; g < 2; g++) acc[n][g] = (f32x4){0.f, 0.f, 0.f, 0.f};

        #pragma unroll
        for (int kp = 0; kp < 2; kp++) {
            int sig = kp * 4 + lg;
            int pa = sig ^ (l15 & 7);
            #pragma unroll
            for (int tap = 0; tap < 9; tap++) {
                const int dy = tap / 3, dx = tap % 3;
                int sl = rbase + r + dy; if (sl >= 10) sl -= 10;
                short8 a0 = *(const short8*)&wls[(tap * 512 + (ch * 32 + l15) * 8 + pa) * 8];
                short8 a1 = *(const short8*)&wls[(tap * 512 + (ch * 32 + 16 + l15) * 8 + pa) * 8];
                #pragma unroll
                for (int n = 0; n < 4; n++) {
                    int xi = n * 16 + l15 + dx;                 // 0..65
                    short8 bf = *(const short8*)&xls[(sl * 528 + xi * 8 + (sig ^ (xi & 7))) * 8];
                    acc[n][0] = __builtin_amdgcn_mfma_f32_16x16x32_bf16(a0, bf, acc[n][0], 0, 0, 0);
                    acc[n][1] = __builtin_amdgcn_mfma_f32_16x16x32_bf16(a1, bf, acc[n][1], 0, 0, 0);
                }
            }
        }

        // ---- store ----
        #pragma unroll
        for (int g = 0; g < 2; g++) {
            float* ob = out + ((size_t)(b * 64 + ch * 32 + g * 16 + lg * 4)) * NPIX
                            + (y0 + r) * 128 + x0 + l15;
            #pragma unroll
            for (int reg = 0; reg < 4; reg++)
                #pragma unroll
                for (int n = 0; n < 4; n++)
                    ob[(size_t)reg * NPIX + n * 16] = acc[n][g][reg];
        }

        if (j < 3) {
            asm volatile("s_waitcnt vmcnt(0)" ::: "memory");   // staged rows landed
            __syncthreads();                                    // everyone past slot reuse
        }
        rbase += 4; if (rbase >= 10) rbase -= 10;
    }
#undef ZROW
#undef DMAROW
}

extern "C" void kernel_launch(void* const* d_in, const int* in_sizes, int n_in,
                              void* d_out, int out_size, void* d_ws, size_t ws_size,
                              hipStream_t stream) {
    const float* x  = (const float*)d_in[0];
    const float* w1 = (const float*)d_in[1];
    const float* b1 = (const float*)d_in[2];
    const float* w2 = (const float*)d_in[3];
    const float* b2 = (const float*)d_in[4];
    float* out = (float*)d_out;

    float* part = (float*)d_ws;                                   // 128 KB
    short* wT = (short*)((char*)d_ws + 131072);                   // 1.18 MB
    short* xT = (short*)((char*)d_ws + 131072 + 1179648);         // 34.1 MB

    xpose_stats<<<dim3(B_, 8, 16), 256, 0, stream>>>(x, xT, part);
    kern_gen<<<dim3(144), 256, 0, stream>>>(part, w1, b1, w2, b2, wT);
    conv_mfma<<<dim3(B_, 2, 8), 512, 0, stream>>>(xT, wT, out);
}